// Round 14
// baseline (377.471 us; speedup 1.0000x reference)
//
#include <hip/hip_runtime.h>
#include <math.h>

// ---------------------------------------------------------------------------
// JointsGait fused v13 = v12 (375.5us best) + chunked weight-register preload.
// layer = ReLU(((A_hat @ H) @ W + b) * att)  ==  ReLU((A_hat @ (H @ W) + b) * att)
//
// R14: dur invariant to conflicts/occupancy/VALU => the binding constraint
// is per-layer load LATENCY with shallow load-ahead (compiler uses 92 of
// 256 VGPRs; ~4 weight loads in flight -> one ~250cyc L2 latency per ks
// step). This version preloads weight fragments in chunks of 4 ks steps
// (<=16 v8h = 64 VGPR) into named registers BEFORE the chunk's MFMAs:
// one L2 latency per 48 MFMAs instead of per 12. All indices compile-time.
// gcn core otherwise v12 (dbuf H, all-MFMA, 1 barrier/layer, bounds(256,2),
// Zt swizzle with c-bit-3 fold).
// ---------------------------------------------------------------------------

typedef _Float16 f16;
typedef _Float16 v2h __attribute__((ext_vector_type(2)));
typedef _Float16 v4h __attribute__((ext_vector_type(4)));
typedef _Float16 v8h __attribute__((ext_vector_type(8)));
typedef float    v4f __attribute__((ext_vector_type(4)));

namespace {

constexpr int BA[19] = {15,13,16,14,11, 5, 6, 5, 5, 6, 7, 8, 1, 0, 0, 1, 2, 3, 4};
constexpr int BB[19] = {13,11,14,12,12,11,12, 6, 7, 8, 9,10, 2, 1, 2, 3, 4, 5, 6};
constexpr float DINV[17] = {
  0.57735026919f, 0.5f, 0.5f, 0.57735026919f, 0.57735026919f,
  0.44721359550f, 0.44721359550f, 0.57735026919f, 0.57735026919f,
  0.70710678119f, 0.70710678119f, 0.5f, 0.5f,
  0.57735026919f, 0.57735026919f, 0.70710678119f, 0.70710678119f};

// H element index with XOR-chunk swizzle (row stride 256 f16 = 512B).
__device__ __forceinline__ int hswz(int row, int k){
  return row*256 + (k & ~63) + (((((k>>3)&7) ^ (row&7)))<<3) + (k&7);
}
// Zt strip: [32 cols][64 j] f16; f(c) = ((c&7)<<3) ^ ((c&8)<<2).
__device__ __forceinline__ int zswz(int c, int r){
  return c*64 + (r ^ ((c&7)<<3) ^ ((c&8)<<2));
}

__device__ __forceinline__ void ldh2(const f16* p, float* d){
  const v2h v = *(const v2h*)p; d[0]=v[0]; d[1]=v[1];
}

// ---- layer: stage1 Z=H@W (MFMA) -> wave-private Zt -> stage2 A-mix (MFMA) --
// D-frag convention (16x16x32): lane (q,m): A[row=m][k=q*8+jj],
// B[k=q*8+jj][n=m], D[row=q*4+ii][col=m].
// R14: stage1 weight fragments preloaded in chunks of 4 ks steps (<=16 v8h)
// so one L2 round-trip covers 48 MFMAs.
template<int KP, int DOUT>
__device__ __forceinline__ void layer_phase(const f16* __restrict__ src,
    f16* __restrict__ dst, f16* ztw,
    const f16* __restrict__ wp, const float* __restrict__ bias,
    const float (&av3)[3], const v8h (&Bfrag)[3][2],
    int w, int m, int q)
{
  constexpr int NKS = KP/32;
  constexpr int NTW = DOUT/64;             // ctiles per wave (1,2,4)
  constexpr int CT_PER = (NTW>=2)?2:1;     // ctiles per Zt pass (strip=32 cols)
  constexpr int NPASS = NTW/CT_PER;
  constexpr int CHUNK = (NKS >= 4) ? 4 : NKS;   // ks steps per preload batch

  v4f acc[3][NTW];
  #pragma unroll
  for (int a=0;a<3;++a)
    #pragma unroll
    for (int b=0;b<NTW;++b) acc[a][b] = v4f{0.f,0.f,0.f,0.f};

  #pragma unroll
  for (int kc=0; kc<NKS; kc+=CHUNK){
    // batch-issue all weight loads for this chunk (<=16 in flight)
    v8h bfr[CHUNK][NTW];
    #pragma unroll
    for (int kk=0; kk<CHUNK; ++kk)
      #pragma unroll
      for (int nt=0; nt<NTW; ++nt)
        bfr[kk][nt] = *(const v8h*)(wp + ((((w*NTW+nt)*NKS + (kc+kk))*64 + q*16 + m)<<3));
    #pragma unroll
    for (int kk=0; kk<CHUNK; ++kk){
      const int ks = kc + kk;
      v8h af[3];
      #pragma unroll
      for (int mt=0;mt<3;++mt)
        af[mt] = *(const v8h*)(src + hswz(mt*16+m, ks*32 + q*8));
      #pragma unroll
      for (int nt=0;nt<NTW;++nt)
        #pragma unroll
        for (int mt=0;mt<3;++mt)
          acc[mt][nt] = __builtin_amdgcn_mfma_f32_16x16x32_f16(af[mt], bfr[kk][nt], acc[mt][nt], 0,0,0);
    }
  }

  #pragma unroll
  for (int p=0;p<NPASS;++p){
    // Zt write: pass-local cols [0,CT_PER*16)
    #pragma unroll
    for (int nt2=0;nt2<CT_PER;++nt2){
      #pragma unroll
      for (int mt=0;mt<3;++mt){
        v4h z;
        #pragma unroll
        for (int ii=0;ii<4;++ii) z[ii] = (f16)acc[mt][p*CT_PER+nt2][ii];
        *(v4h*)(ztw + zswz(nt2*16+m, mt*16+q*4)) = z;
      }
    }
    // stage2 on the same cols (same-wave LDS ordering; no barrier)
    #pragma unroll
    for (int ct2=0;ct2<CT_PER;++ct2){
      const v8h za0 = *(const v8h*)(ztw + zswz(ct2*16+m, q*8));
      const v8h za1 = *(const v8h*)(ztw + zswz(ct2*16+m, 32 + q*8));
      v4f a2[3];
      #pragma unroll
      for (int mt=0;mt<3;++mt) a2[mt] = v4f{0.f,0.f,0.f,0.f};
      #pragma unroll
      for (int mt=0;mt<3;++mt)
        a2[mt] = __builtin_amdgcn_mfma_f32_16x16x32_f16(za0, Bfrag[mt][0], a2[mt], 0,0,0);
      #pragma unroll
      for (int mt=0;mt<3;++mt)
        a2[mt] = __builtin_amdgcn_mfma_f32_16x16x32_f16(za1, Bfrag[mt][1], a2[mt], 0,0,0);
      const int cb = w*(DOUT/4) + (p*CT_PER+ct2)*16 + q*4;
      const v4f b4 = *(const v4f*)(bias + cb);
      #pragma unroll
      for (int mt=0;mt<3;++mt){
        v4h o;
        #pragma unroll
        for (int ii=0;ii<4;++ii)
          o[ii] = (f16)fmaxf((a2[mt][ii] + b4[ii])*av3[mt], 0.f);
        *(v4h*)(dst + hswz(mt*16+m, cb)) = o;
      }
    }
  }
}

} // namespace

// ---------------- prep: Wpack (B-frag order, k-padded), A-table, fcW, BN ----
__global__ void prep_kernel(
    const float* __restrict__ W1, const float* __restrict__ W2,
    const float* __restrict__ W3, const float* __restrict__ W4,
    const float* __restrict__ W5, const float* __restrict__ W6,
    const float* __restrict__ W7, const float* __restrict__ W8,
    const float* __restrict__ W9,
    const float* __restrict__ B1, const float* __restrict__ B2,
    const float* __restrict__ B3, const float* __restrict__ B4,
    const float* __restrict__ B5, const float* __restrict__ B6,
    const float* __restrict__ B7, const float* __restrict__ B8,
    const float* __restrict__ B9,
    const float* __restrict__ fcW, const float* __restrict__ bng,
    const float* __restrict__ bnb, const float* __restrict__ bnrm,
    const float* __restrict__ bnrv, const float* __restrict__ att,
    f16* __restrict__ wt, f16* __restrict__ Ath, f16* __restrict__ fcWh,
    float* __restrict__ bnsc, float* __restrict__ bnsh,
    float* __restrict__ bcat, float* __restrict__ attp, int G)
{
  const int idx = blockIdx.x*blockDim.x + threadIdx.x;
  const int stride = gridDim.x*blockDim.x;
  const float* Ws[9] = {W1,W2,W3,W4,W5,W6,W7,W8,W9};
  const float* Bs[9] = {B1,B2,B3,B4,B5,B6,B7,B8,B9};
  const int DINs[9]  = {2,64,64,64,128,128,128,256,256};
  const int DOUTs[9] = {64,64,64,128,128,128,256,256,256};
  const int KPs[9]   = {32,64,64,64,128,128,128,256,256};
  const int OFFs[9]  = {0,2048,6144,10240,18432,34816,51200,83968,149504};
  const int BOFFs[9] = {0,64,128,192,320,448,576,832,1088};
  for (int l=0;l<9;++l){
    const float* W = Ws[l];
    const int DIN=DINs[l], DOUT=DOUTs[l], KP=KPs[l], NKS=KP>>5;
    f16* dst = wt + OFFs[l];
    const int n = DOUT*KP;
    for (int i=idx;i<n;i+=stride){
      // Wpack[(((ct*NKS+ks)*4+q)*16+m)*8+jj] = W[ks*32+q*8+jj][ct*16+m]
      const int jj = i&7, mm = (i>>3)&15, qq = (i>>7)&3, r2 = i>>9;
      const int ks = r2 & (NKS-1), ct = r2 / NKS;
      const int k = ks*32 + qq*8 + jj, c = ct*16 + mm;
      dst[i] = (k<DIN) ? (f16)W[k*DOUT + c] : (f16)0.f;
    }
    for (int i=idx;i<DOUT;i+=stride) bcat[BOFFs[l]+i] = Bs[l][i];
  }
  // A-table: At[r][j] (48 x 64 f16), block-diag 2x padded A_hat, symmetric.
  for (int i=idx;i<48*64;i+=stride){
    const int r = i>>6, j = i&63;
    float v = 0.f;
    if (j < 48 && ((r<24) == (j<24))){
      const int a = (r<24)? r : r-24;
      const int b = (j<24)? j : j-24;
      if (a<17 && b<17){
        bool adj = (a==b);
        #pragma unroll
        for (int e=0;e<19;++e)
          adj = adj || (BA[e]==a && BB[e]==b) || (BA[e]==b && BB[e]==a);
        if (adj) v = DINV[a]*DINV[b];
      }
    }
    Ath[i] = (f16)v;
  }
  for (int i=idx;i<6*256*256;i+=stride) fcWh[i] = (f16)fcW[i];
  for (int i=idx;i<1536;i+=stride){
    const float sc = bng[i] * rsqrtf(bnrv[i] + 1e-5f);
    bnsc[i] = sc; bnsh[i] = bnb[i] - bnrm[i]*sc;
  }
  const int G2 = (G+1)&~1;
  for (int i=idx;i<G2*24;i+=stride){
    const int g = i/24, j = i - g*24;
    attp[i] = (j<17 && g<G) ? att[(size_t)g*17 + j] : 0.f;
  }
}

// ---------------- fused GCN (9 layers, all-MFMA, dbuf H) + pooling -----------
__global__ __launch_bounds__(256, 2)
void gcn_kernel(const float* __restrict__ x, const f16* __restrict__ wt,
                const f16* __restrict__ Ath, const float* __restrict__ attp,
                const float* __restrict__ bcat,
                f16* __restrict__ pooled, int G)
{
  __shared__ __align__(16) f16 Hb[2][48*256];   // 2 x 24576 B
  __shared__ __align__(16) f16 Zt[4*2048];      // 4 waves x (32 cols x 64 j)
  const int t = threadIdx.x, w = t>>6, lane = t&63;
  const int m = lane&15, q = lane>>4;
  const int g0 = blockIdx.x*2;
  f16* ztw = Zt + w*2048;

  // persistent A_blk B-fragments + att row values
  v8h Bfrag[3][2];
  #pragma unroll
  for (int mt=0;mt<3;++mt)
    #pragma unroll
    for (int ks2=0;ks2<2;++ks2)
      Bfrag[mt][ks2] = *(const v8h*)(Ath + (mt*16+m)*64 + ks2*32 + q*8);
  float av3[3];
  #pragma unroll
  for (int mt=0;mt<3;++mt) av3[mt] = attp[g0*24 + mt*16 + m];

  // init: H = raw x in cols 0..1 (zeros to col 32); zero Zt
  {
    const v8h z8 = {0,0,0,0,0,0,0,0};
    #pragma unroll
    for (int i=0;i<4;++i) *(v8h*)(Zt + t*32 + i*8) = z8;
    const int g = t>>7, kk = t&127;
    if (kk < 32){
      #pragma unroll
      for (int i=0;i<17;++i){
        float v = 0.f;
        if (kk < 2 && g0+g < G) v = x[(size_t)(g0+g)*34 + i*2 + kk];
        Hb[0][hswz(g*24+i, kk)] = (f16)v;
      }
      #pragma unroll
      for (int j=17;j<24;++j) Hb[0][hswz(g*24+j, kk)] = (f16)0.f;
    }
  }
  __syncthreads();

  layer_phase< 32, 64>(Hb[0], Hb[1], ztw, wt+0,      bcat+0,    av3, Bfrag, w, m, q); __syncthreads();
  layer_phase< 64, 64>(Hb[1], Hb[0], ztw, wt+2048,   bcat+64,   av3, Bfrag, w, m, q); __syncthreads();
  layer_phase< 64, 64>(Hb[0], Hb[1], ztw, wt+6144,   bcat+128,  av3, Bfrag, w, m, q); __syncthreads();
  layer_phase< 64,128>(Hb[1], Hb[0], ztw, wt+10240,  bcat+192,  av3, Bfrag, w, m, q); __syncthreads();
  layer_phase<128,128>(Hb[0], Hb[1], ztw, wt+18432,  bcat+320,  av3, Bfrag, w, m, q); __syncthreads();
  layer_phase<128,128>(Hb[1], Hb[0], ztw, wt+34816,  bcat+448,  av3, Bfrag, w, m, q); __syncthreads();
  layer_phase<128,256>(Hb[0], Hb[1], ztw, wt+51200,  bcat+576,  av3, Bfrag, w, m, q); __syncthreads();
  layer_phase<256,256>(Hb[1], Hb[0], ztw, wt+83968,  bcat+832,  av3, Bfrag, w, m, q); __syncthreads();
  layer_phase<256,256>(Hb[0], Hb[1], ztw, wt+149504, bcat+1088, av3, Bfrag, w, m, q); __syncthreads();

  // ---- JRPP pooling from Hb[1]: v2h column pairs, 128 threads/graph -------
  const int g = t>>7, tt = t&127, k0 = tt*2, gg = g0 + g;
  if (gg < G){
    float sA[2]={0,0}, sB[2]={0,0}, sH[2]={0,0}, sL[2]={0,0}, sR[2]={0,0};
    #pragma unroll
    for (int i=0;i<17;++i){
      float hi[2];
      ldh2(&Hb[1][hswz(g*24+i, k0)], hi);
      #pragma unroll
      for (int v=0;v<2;++v){
        if (i<11) sA[v]+=hi[v]; else sB[v]+=hi[v];
        if (i<5)  sH[v]+=hi[v];
        if (i==5||i==7||i==9||i==12||i==14||i==16)  sL[v]+=hi[v];
        if (i==6||i==8||i==10||i==11||i==13||i==15) sR[v]+=hi[v];
      }
    }
    f16* op = pooled + (size_t)gg*1536 + k0;
    v2h o;
    #pragma unroll
    for (int v=0;v<2;++v) o[v]=(f16)((sA[v]+sB[v])*(1.0f/17.0f)); *(v2h*)(op+0*256)=o;
    #pragma unroll
    for (int v=0;v<2;++v) o[v]=(f16)(sA[v]*(1.0f/11.0f));         *(v2h*)(op+1*256)=o;
    #pragma unroll
    for (int v=0;v<2;++v) o[v]=(f16)(sB[v]*(1.0f/6.0f));          *(v2h*)(op+2*256)=o;
    #pragma unroll
    for (int v=0;v<2;++v) o[v]=(f16)(sH[v]*(1.0f/5.0f));          *(v2h*)(op+3*256)=o;
    #pragma unroll
    for (int v=0;v<2;++v) o[v]=(f16)(sL[v]*(1.0f/6.0f));          *(v2h*)(op+4*256)=o;
    #pragma unroll
    for (int v=0;v<2;++v) o[v]=(f16)(sR[v]*(1.0f/6.0f));          *(v2h*)(op+5*256)=o;
  }
}

// ---------------- head: stage once, 288 MFMA straight-line, BN + L2-norm -----
__global__ __launch_bounds__(256, 3)
void head_kernel(const f16* __restrict__ pooled, const f16* __restrict__ fcWh,
                 const float* __restrict__ fcB, const float* __restrict__ bnsc,
                 const float* __restrict__ bnsh, float* __restrict__ out, int G)
{
  __shared__ __align__(16) f16 Ap[16*1536];   // 49152 B, swizzled
  __shared__ float red[64];
  __shared__ float invn[16];
  const int t = threadIdx.x, w = t>>6, lane = t&63;
  const int m = lane&15, q = lane>>4;
  const int g0 = blockIdx.x*16;
  const int cb = w*64;

  // stage pooled rows (all 6 scales) once
  for (int id=t; id<16*192; id+=256){
    const int row = id/192, cc = id - row*192;
    v8h v = v8h{0,0,0,0,0,0,0,0};
    const int gg = g0 + row;
    if (gg < G) v = *(const v8h*)(pooled + (size_t)gg*1536 + cc*8);
    const int pc = (cc & ~7) | ((cc&7) ^ (row&7));
    *(v8h*)(Ap + row*1536 + pc*8) = v;
  }
  __syncthreads();

  v4f acc[6][4];
  #pragma unroll
  for (int s=0;s<6;++s)
    #pragma unroll
    for (int nt=0;nt<4;++nt) acc[s][nt] = v4f{0.f,0.f,0.f,0.f};

  #pragma unroll
  for (int s=0;s<6;++s){
    #pragma unroll
    for (int ks=0; ks<8; ++ks){
      const int c = s*32 + ks*4 + q;
      const v8h af = *(const v8h*)(Ap + m*1536 + ((c & ~7) | ((c&7) ^ (m&7)))*8);
      #pragma unroll
      for (int nt=0;nt<4;++nt){
        const v8h bf = *(const v8h*)(fcWh + (size_t)(s*256 + cb + nt*16 + m)*256 + ks*32 + q*8);
        acc[s][nt] = __builtin_amdgcn_mfma_f32_16x16x32_f16(af, bf, acc[s][nt], 0,0,0);
      }
    }
  }

  // BN in place + per-graph sum of squares
  float ss[4] = {0.f,0.f,0.f,0.f};
  #pragma unroll
  for (int s=0;s<6;++s)
    #pragma unroll
    for (int nt=0;nt<4;++nt){
      const int idx = s*256 + cb + nt*16 + m;
      const float bc = fcB[idx], sc = bnsc[idx], sh = bnsh[idx];
      #pragma unroll
      for (int i=0;i<4;++i){
        const float f = (acc[s][nt][i] + bc)*sc + sh;
        acc[s][nt][i] = f;
        ss[i] += f*f;
      }
    }

  #pragma unroll
  for (int off=1; off<16; off<<=1)
    #pragma unroll
    for (int i=0;i<4;++i) ss[i] += __shfl_xor(ss[i], off, 64);
  if (m==0)
    #pragma unroll
    for (int i=0;i<4;++i) red[w*16 + q*4 + i] = ss[i];
  __syncthreads();
  if (t < 16){
    const float s4 = red[t] + red[16+t] + red[32+t] + red[48+t];
    invn[t] = 1.f / fmaxf(sqrtf(s4), 1e-12f);
  }
  __syncthreads();
  float iv[4];
  #pragma unroll
  for (int i=0;i<4;++i) iv[i] = invn[q*4+i];
  #pragma unroll
  for (int s=0;s<6;++s)
    #pragma unroll
    for (int nt=0;nt<4;++nt)
      #pragma unroll
      for (int i=0;i<4;++i){
        const int gg = g0 + q*4 + i;
        if (gg < G)
          out[(size_t)gg*1536 + s*256 + cb + nt*16 + m] = acc[s][nt][i]*iv[i];
      }
}

extern "C" void kernel_launch(void* const* d_in, const int* in_sizes, int n_in,
                              void* d_out, int out_size, void* d_ws, size_t ws_size,
                              hipStream_t stream) {
  (void)n_in; (void)out_size; (void)ws_size;
  const float* x   = (const float*)d_in[0];
  const float* att = (const float*)d_in[1];
  const float* W[9]; const float* B[9];
  for (int i=0;i<9;i++){ W[i]=(const float*)d_in[3+2*i]; B[i]=(const float*)d_in[4+2*i]; }
  const float* fcW  = (const float*)d_in[21];
  const float* fcB  = (const float*)d_in[22];
  const float* bn_g = (const float*)d_in[23];
  const float* bn_b = (const float*)d_in[24];
  const float* bn_rm= (const float*)d_in[25];
  const float* bn_rv= (const float*)d_in[26];
  float* out = (float*)d_out;

  const int G = in_sizes[1] / 17;
  const int G2 = (G+1)&~1;

  // ws layout
  char* ws = (char*)d_ws;
  f16*   wt   = (f16*)(ws);                       // 430080 B
  f16*   fcWh = (f16*)(ws + 430080);              // 786432 B -> ends 1216512
  float* bnsc = (float*)(ws + 1216512);           // 6144 B
  float* bnsh = (float*)(ws + 1222656);           // 6144 B
  float* bcat = (float*)(ws + 1228800);           // 5376 B -> ends 1234176
  f16*   Ath  = (f16*)(ws + 1234176);             // 6144 B -> ends 1240320
  float* attp = (float*)(ws + 1240320);           // G2*24*4 B
  size_t poolOff = (1240320 + (size_t)G2*96 + 255) & ~(size_t)255;
  f16* pooled = (f16*)(ws + poolOff);             // G*1536*2 B

  prep_kernel<<<2048, 256, 0, stream>>>(
      W[0],W[1],W[2],W[3],W[4],W[5],W[6],W[7],W[8],
      B[0],B[1],B[2],B[3],B[4],B[5],B[6],B[7],B[8],
      fcW, bn_g, bn_b, bn_rm, bn_rv, att,
      wt, Ath, fcWh, bnsc, bnsh, bcat, attp, G);

  const int gb = (G + 1) / 2;
  gcn_kernel<<<gb, 256, 0, stream>>>(
      x, wt, Ath, attp, bcat, pooled, G);

  head_kernel<<<(G + 15)/16, 256, 0, stream>>>(
      pooled, fcWh, fcB, bnsc, bnsh, out, G);
}

// Round 15
// 344.324 us; speedup vs baseline: 1.0963x; 1.0963x over previous
//
#include <hip/hip_runtime.h>
#include <math.h>

// ---------------------------------------------------------------------------
// JointsGait fused v14 = v12 gcn (best: 195us, total 375.5) + fcW packed in
// B-fragment order for head.
// layer = ReLU(((A_hat @ H) @ W + b) * att)  ==  ReLU((A_hat @ (H @ W) + b) * att)
//
// R15: gcn is a latency plateau (10 experiments: 193-200us invariant to
// occupancy/barriers/VALU/conflicts/load-batching) -> attack the 182us
// residual. Address arithmetic on head's B-loads: fcWh[(out)*256+k] has
// lane stride 512B -> every 16B lane-load touches its own 64B line -> 64
// L2 line-requests/instruction (4x waste), ~2GB line traffic/iter, est.
// 60-100us. Fix = same B-fragment pre-pack already used for gcn weights:
// per scale s (256x256, 8 ks steps), fcWp[s][((ct*8+ks)*64 + q*16+m)*8+jj]
//  = fcW[s][ct*16+m][ks*32+q*8+jj]; head's wave then reads 1KB contiguous
// per (s,nt,ks). R14's chunk preload reverted (compiler folded it, -2%).
// ---------------------------------------------------------------------------

typedef _Float16 f16;
typedef _Float16 v2h __attribute__((ext_vector_type(2)));
typedef _Float16 v4h __attribute__((ext_vector_type(4)));
typedef _Float16 v8h __attribute__((ext_vector_type(8)));
typedef float    v4f __attribute__((ext_vector_type(4)));

namespace {

constexpr int BA[19] = {15,13,16,14,11, 5, 6, 5, 5, 6, 7, 8, 1, 0, 0, 1, 2, 3, 4};
constexpr int BB[19] = {13,11,14,12,12,11,12, 6, 7, 8, 9,10, 2, 1, 2, 3, 4, 5, 6};
constexpr float DINV[17] = {
  0.57735026919f, 0.5f, 0.5f, 0.57735026919f, 0.57735026919f,
  0.44721359550f, 0.44721359550f, 0.57735026919f, 0.57735026919f,
  0.70710678119f, 0.70710678119f, 0.5f, 0.5f,
  0.57735026919f, 0.57735026919f, 0.70710678119f, 0.70710678119f};

// H element index with XOR-chunk swizzle (row stride 256 f16 = 512B).
__device__ __forceinline__ int hswz(int row, int k){
  return row*256 + (k & ~63) + (((((k>>3)&7) ^ (row&7)))<<3) + (k&7);
}
// Zt strip: [32 cols][64 j] f16; f(c) = ((c&7)<<3) ^ ((c&8)<<2).
__device__ __forceinline__ int zswz(int c, int r){
  return c*64 + (r ^ ((c&7)<<3) ^ ((c&8)<<2));
}

__device__ __forceinline__ void ldh2(const f16* p, float* d){
  const v2h v = *(const v2h*)p; d[0]=v[0]; d[1]=v[1];
}

// ---- layer: stage1 Z=H@W (MFMA) -> wave-private Zt -> stage2 A-mix (MFMA) --
// D-frag convention (16x16x32): lane (q,m): A[row=m][k=q*8+jj],
// B[k=q*8+jj][n=m], D[row=q*4+ii][col=m].
template<int KP, int DOUT>
__device__ __forceinline__ void layer_phase(const f16* __restrict__ src,
    f16* __restrict__ dst, f16* ztw,
    const f16* __restrict__ wp, const float* __restrict__ bias,
    const float (&av3)[3], const v8h (&Bfrag)[3][2],
    int w, int m, int q)
{
  constexpr int NKS = KP/32;
  constexpr int NTW = DOUT/64;             // ctiles per wave (1,2,4)
  constexpr int CT_PER = (NTW>=2)?2:1;     // ctiles per Zt pass (strip=32 cols)
  constexpr int NPASS = NTW/CT_PER;

  v4f acc[3][NTW];
  #pragma unroll
  for (int a=0;a<3;++a)
    #pragma unroll
    for (int b=0;b<NTW;++b) acc[a][b] = v4f{0.f,0.f,0.f,0.f};

  #pragma unroll
  for (int ks=0; ks<NKS; ++ks){
    v8h af[3];
    #pragma unroll
    for (int mt=0;mt<3;++mt)
      af[mt] = *(const v8h*)(src + hswz(mt*16+m, ks*32 + q*8));
    #pragma unroll
    for (int nt=0;nt<NTW;++nt){
      const v8h bf = *(const v8h*)(wp + ((((w*NTW+nt)*NKS + ks)*64 + q*16 + m)<<3));
      #pragma unroll
      for (int mt=0;mt<3;++mt)
        acc[mt][nt] = __builtin_amdgcn_mfma_f32_16x16x32_f16(af[mt], bf, acc[mt][nt], 0,0,0);
    }
  }

  #pragma unroll
  for (int p=0;p<NPASS;++p){
    // Zt write: pass-local cols [0,CT_PER*16)
    #pragma unroll
    for (int nt2=0;nt2<CT_PER;++nt2){
      #pragma unroll
      for (int mt=0;mt<3;++mt){
        v4h z;
        #pragma unroll
        for (int ii=0;ii<4;++ii) z[ii] = (f16)acc[mt][p*CT_PER+nt2][ii];
        *(v4h*)(ztw + zswz(nt2*16+m, mt*16+q*4)) = z;
      }
    }
    // stage2 on the same cols (same-wave LDS ordering; no barrier)
    #pragma unroll
    for (int ct2=0;ct2<CT_PER;++ct2){
      const v8h za0 = *(const v8h*)(ztw + zswz(ct2*16+m, q*8));
      const v8h za1 = *(const v8h*)(ztw + zswz(ct2*16+m, 32 + q*8));
      v4f a2[3];
      #pragma unroll
      for (int mt=0;mt<3;++mt) a2[mt] = v4f{0.f,0.f,0.f,0.f};
      #pragma unroll
      for (int mt=0;mt<3;++mt)
        a2[mt] = __builtin_amdgcn_mfma_f32_16x16x32_f16(za0, Bfrag[mt][0], a2[mt], 0,0,0);
      #pragma unroll
      for (int mt=0;mt<3;++mt)
        a2[mt] = __builtin_amdgcn_mfma_f32_16x16x32_f16(za1, Bfrag[mt][1], a2[mt], 0,0,0);
      const int cb = w*(DOUT/4) + (p*CT_PER+ct2)*16 + q*4;
      const v4f b4 = *(const v4f*)(bias + cb);
      #pragma unroll
      for (int mt=0;mt<3;++mt){
        v4h o;
        #pragma unroll
        for (int ii=0;ii<4;++ii)
          o[ii] = (f16)fmaxf((a2[mt][ii] + b4[ii])*av3[mt], 0.f);
        *(v4h*)(dst + hswz(mt*16+m, cb)) = o;
      }
    }
  }
}

} // namespace

// ---------------- prep: Wpack + fcW B-frag pack + A-table + BN fold ---------
__global__ void prep_kernel(
    const float* __restrict__ W1, const float* __restrict__ W2,
    const float* __restrict__ W3, const float* __restrict__ W4,
    const float* __restrict__ W5, const float* __restrict__ W6,
    const float* __restrict__ W7, const float* __restrict__ W8,
    const float* __restrict__ W9,
    const float* __restrict__ B1, const float* __restrict__ B2,
    const float* __restrict__ B3, const float* __restrict__ B4,
    const float* __restrict__ B5, const float* __restrict__ B6,
    const float* __restrict__ B7, const float* __restrict__ B8,
    const float* __restrict__ B9,
    const float* __restrict__ fcW, const float* __restrict__ bng,
    const float* __restrict__ bnb, const float* __restrict__ bnrm,
    const float* __restrict__ bnrv, const float* __restrict__ att,
    f16* __restrict__ wt, f16* __restrict__ Ath, f16* __restrict__ fcWh,
    float* __restrict__ bnsc, float* __restrict__ bnsh,
    float* __restrict__ bcat, float* __restrict__ attp, int G)
{
  const int idx = blockIdx.x*blockDim.x + threadIdx.x;
  const int stride = gridDim.x*blockDim.x;
  const float* Ws[9] = {W1,W2,W3,W4,W5,W6,W7,W8,W9};
  const float* Bs[9] = {B1,B2,B3,B4,B5,B6,B7,B8,B9};
  const int DINs[9]  = {2,64,64,64,128,128,128,256,256};
  const int DOUTs[9] = {64,64,64,128,128,128,256,256,256};
  const int KPs[9]   = {32,64,64,64,128,128,128,256,256};
  const int OFFs[9]  = {0,2048,6144,10240,18432,34816,51200,83968,149504};
  const int BOFFs[9] = {0,64,128,192,320,448,576,832,1088};
  for (int l=0;l<9;++l){
    const float* W = Ws[l];
    const int DIN=DINs[l], DOUT=DOUTs[l], KP=KPs[l], NKS=KP>>5;
    f16* dst = wt + OFFs[l];
    const int n = DOUT*KP;
    for (int i=idx;i<n;i+=stride){
      // Wpack[(((ct*NKS+ks)*4+q)*16+m)*8+jj] = W[ks*32+q*8+jj][ct*16+m]
      const int jj = i&7, mm = (i>>3)&15, qq = (i>>7)&3, r2 = i>>9;
      const int ks = r2 & (NKS-1), ct = r2 / NKS;
      const int k = ks*32 + qq*8 + jj, c = ct*16 + mm;
      dst[i] = (k<DIN) ? (f16)W[k*DOUT+c] : (f16)0.f;
    }
    for (int i=idx;i<DOUT;i+=stride) bcat[BOFFs[l]+i] = Bs[l][i];
  }
  // A-table: At[r][j] (48 x 64 f16), block-diag 2x padded A_hat, symmetric.
  for (int i=idx;i<48*64;i+=stride){
    const int r = i>>6, j = i&63;
    float v = 0.f;
    if (j < 48 && ((r<24) == (j<24))){
      const int a = (r<24)? r : r-24;
      const int b = (j<24)? j : j-24;
      if (a<17 && b<17){
        bool adj = (a==b);
        #pragma unroll
        for (int e=0;e<19;++e)
          adj = adj || (BA[e]==a && BB[e]==b) || (BA[e]==b && BB[e]==a);
        if (adj) v = DINV[a]*DINV[b];
      }
    }
    Ath[i] = (f16)v;
  }
  // fcW B-fragment pack, per scale s (256x256, NKS=8):
  // fcWh[s*65536 + ((ct*8+ks)*64 + q*16+m)*8+jj] = fcW[s][ct*16+m][ks*32+q*8+jj]
  for (int i=idx;i<6*65536;i+=stride){
    const int s = i>>16, j = i&65535;
    const int jj = j&7, mm = (j>>3)&15, qq = (j>>7)&3, r2 = j>>9;
    const int ks = r2&7, ct = r2>>3;
    const int k = ks*32 + qq*8 + jj, c = ct*16 + mm;
    fcWh[i] = (f16)fcW[(size_t)s*65536 + c*256 + k];
  }
  for (int i=idx;i<1536;i+=stride){
    const float sc = bng[i] * rsqrtf(bnrv[i] + 1e-5f);
    bnsc[i] = sc; bnsh[i] = bnb[i] - bnrm[i]*sc;
  }
  const int G2 = (G+1)&~1;
  for (int i=idx;i<G2*24;i+=stride){
    const int g = i/24, j = i - g*24;
    attp[i] = (j<17 && g<G) ? att[(size_t)g*17 + j] : 0.f;
  }
}

// ---------------- fused GCN (9 layers, all-MFMA, dbuf H) + pooling -----------
__global__ __launch_bounds__(256, 2)
void gcn_kernel(const float* __restrict__ x, const f16* __restrict__ wt,
                const f16* __restrict__ Ath, const float* __restrict__ attp,
                const float* __restrict__ bcat,
                f16* __restrict__ pooled, int G)
{
  __shared__ __align__(16) f16 Hb[2][48*256];   // 2 x 24576 B
  __shared__ __align__(16) f16 Zt[4*2048];      // 4 waves x (32 cols x 64 j)
  const int t = threadIdx.x, w = t>>6, lane = t&63;
  const int m = lane&15, q = lane>>4;
  const int g0 = blockIdx.x*2;
  f16* ztw = Zt + w*2048;

  // persistent A_blk B-fragments + att row values
  v8h Bfrag[3][2];
  #pragma unroll
  for (int mt=0;mt<3;++mt)
    #pragma unroll
    for (int ks2=0;ks2<2;++ks2)
      Bfrag[mt][ks2] = *(const v8h*)(Ath + (mt*16+m)*64 + ks2*32 + q*8);
  float av3[3];
  #pragma unroll
  for (int mt=0;mt<3;++mt) av3[mt] = attp[g0*24 + mt*16 + m];

  // init: H = raw x in cols 0..1 (zeros to col 32); zero Zt
  {
    const v8h z8 = {0,0,0,0,0,0,0,0};
    #pragma unroll
    for (int i=0;i<4;++i) *(v8h*)(Zt + t*32 + i*8) = z8;
    const int g = t>>7, kk = t&127;
    if (kk < 32){
      #pragma unroll
      for (int i=0;i<17;++i){
        float v = 0.f;
        if (kk < 2 && g0+g < G) v = x[(size_t)(g0+g)*34 + i*2 + kk];
        Hb[0][hswz(g*24+i, kk)] = (f16)v;
      }
      #pragma unroll
      for (int j=17;j<24;++j) Hb[0][hswz(g*24+j, kk)] = (f16)0.f;
    }
  }
  __syncthreads();

  layer_phase< 32, 64>(Hb[0], Hb[1], ztw, wt+0,      bcat+0,    av3, Bfrag, w, m, q); __syncthreads();
  layer_phase< 64, 64>(Hb[1], Hb[0], ztw, wt+2048,   bcat+64,   av3, Bfrag, w, m, q); __syncthreads();
  layer_phase< 64, 64>(Hb[0], Hb[1], ztw, wt+6144,   bcat+128,  av3, Bfrag, w, m, q); __syncthreads();
  layer_phase< 64,128>(Hb[1], Hb[0], ztw, wt+10240,  bcat+192,  av3, Bfrag, w, m, q); __syncthreads();
  layer_phase<128,128>(Hb[0], Hb[1], ztw, wt+18432,  bcat+320,  av3, Bfrag, w, m, q); __syncthreads();
  layer_phase<128,128>(Hb[1], Hb[0], ztw, wt+34816,  bcat+448,  av3, Bfrag, w, m, q); __syncthreads();
  layer_phase<128,256>(Hb[0], Hb[1], ztw, wt+51200,  bcat+576,  av3, Bfrag, w, m, q); __syncthreads();
  layer_phase<256,256>(Hb[1], Hb[0], ztw, wt+83968,  bcat+832,  av3, Bfrag, w, m, q); __syncthreads();
  layer_phase<256,256>(Hb[0], Hb[1], ztw, wt+149504, bcat+1088, av3, Bfrag, w, m, q); __syncthreads();

  // ---- JRPP pooling from Hb[1]: v2h column pairs, 128 threads/graph -------
  const int g = t>>7, tt = t&127, k0 = tt*2, gg = g0 + g;
  if (gg < G){
    float sA[2]={0,0}, sB[2]={0,0}, sH[2]={0,0}, sL[2]={0,0}, sR[2]={0,0};
    #pragma unroll
    for (int i=0;i<17;++i){
      float hi[2];
      ldh2(&Hb[1][hswz(g*24+i, k0)], hi);
      #pragma unroll
      for (int v=0;v<2;++v){
        if (i<11) sA[v]+=hi[v]; else sB[v]+=hi[v];
        if (i<5)  sH[v]+=hi[v];
        if (i==5||i==7||i==9||i==12||i==14||i==16)  sL[v]+=hi[v];
        if (i==6||i==8||i==10||i==11||i==13||i==15) sR[v]+=hi[v];
      }
    }
    f16* op = pooled + (size_t)gg*1536 + k0;
    v2h o;
    #pragma unroll
    for (int v=0;v<2;++v) o[v]=(f16)((sA[v]+sB[v])*(1.0f/17.0f)); *(v2h*)(op+0*256)=o;
    #pragma unroll
    for (int v=0;v<2;++v) o[v]=(f16)(sA[v]*(1.0f/11.0f));         *(v2h*)(op+1*256)=o;
    #pragma unroll
    for (int v=0;v<2;++v) o[v]=(f16)(sB[v]*(1.0f/6.0f));          *(v2h*)(op+2*256)=o;
    #pragma unroll
    for (int v=0;v<2;++v) o[v]=(f16)(sH[v]*(1.0f/5.0f));          *(v2h*)(op+3*256)=o;
    #pragma unroll
    for (int v=0;v<2;++v) o[v]=(f16)(sL[v]*(1.0f/6.0f));          *(v2h*)(op+4*256)=o;
    #pragma unroll
    for (int v=0;v<2;++v) o[v]=(f16)(sR[v]*(1.0f/6.0f));          *(v2h*)(op+5*256)=o;
  }
}

// ---------------- head: stage once, 288 MFMA straight-line, BN + L2-norm -----
__global__ __launch_bounds__(256, 3)
void head_kernel(const f16* __restrict__ pooled, const f16* __restrict__ fcWh,
                 const float* __restrict__ fcB, const float* __restrict__ bnsc,
                 const float* __restrict__ bnsh, float* __restrict__ out, int G)
{
  __shared__ __align__(16) f16 Ap[16*1536];   // 49152 B, swizzled
  __shared__ float red[64];
  __shared__ float invn[16];
  const int t = threadIdx.x, w = t>>6, lane = t&63;
  const int m = lane&15, q = lane>>4;
  const int g0 = blockIdx.x*16;
  const int cb = w*64;

  // stage pooled rows (all 6 scales) once
  for (int id=t; id<16*192; id+=256){
    const int row = id/192, cc = id - row*192;
    v8h v = v8h{0,0,0,0,0,0,0,0};
    const int gg = g0 + row;
    if (gg < G) v = *(const v8h*)(pooled + (size_t)gg*1536 + cc*8);
    const int pc = (cc & ~7) | ((cc&7) ^ (row&7));
    *(v8h*)(Ap + row*1536 + pc*8) = v;
  }
  __syncthreads();

  v4f acc[6][4];
  #pragma unroll
  for (int s=0;s<6;++s)
    #pragma unroll
    for (int nt=0;nt<4;++nt) acc[s][nt] = v4f{0.f,0.f,0.f,0.f};

  #pragma unroll
  for (int s=0;s<6;++s){
    #pragma unroll
    for (int ks=0; ks<8; ++ks){
      const int c = s*32 + ks*4 + q;
      const v8h af = *(const v8h*)(Ap + m*1536 + ((c & ~7) | ((c&7) ^ (m&7)))*8);
      #pragma unroll
      for (int nt=0;nt<4;++nt){
        // B-fragment-packed fcW: wave reads 1KB contiguous per (s,nt,ks)
        const v8h bf = *(const v8h*)(fcWh + (size_t)s*65536 +
                         (((((w*4+nt)*8 + ks)*64) + q*16 + m)<<3));
        acc[s][nt] = __builtin_amdgcn_mfma_f32_16x16x32_f16(af, bf, acc[s][nt], 0,0,0);
      }
    }
  }

  // BN in place + per-graph sum of squares
  float ss[4] = {0.f,0.f,0.f,0.f};
  #pragma unroll
  for (int s=0;s<6;++s)
    #pragma unroll
    for (int nt=0;nt<4;++nt){
      const int idx = s*256 + cb + nt*16 + m;
      const float bc = fcB[idx], sc = bnsc[idx], sh = bnsh[idx];
      #pragma unroll
      for (int i=0;i<4;++i){
        const float f = (acc[s][nt][i] + bc)*sc + sh;
        acc[s][nt][i] = f;
        ss[i] += f*f;
      }
    }

  #pragma unroll
  for (int off=1; off<16; off<<=1)
    #pragma unroll
    for (int i=0;i<4;++i) ss[i] += __shfl_xor(ss[i], off, 64);
  if (m==0)
    #pragma unroll
    for (int i=0;i<4;++i) red[w*16 + q*4 + i] = ss[i];
  __syncthreads();
  if (t < 16){
    const float s4 = red[t] + red[16+t] + red[32+t] + red[48+t];
    invn[t] = 1.f / fmaxf(sqrtf(s4), 1e-12f);
  }
  __syncthreads();
  float iv[4];
  #pragma unroll
  for (int i=0;i<4;++i) iv[i] = invn[q*4+i];
  #pragma unroll
  for (int s=0;s<6;++s)
    #pragma unroll
    for (int nt=0;nt<4;++nt)
      #pragma unroll
      for (int i=0;i<4;++i){
        const int gg = g0 + q*4 + i;
        if (gg < G)
          out[(size_t)gg*1536 + s*256 + cb + nt*16 + m] = acc[s][nt][i]*iv[i];
      }
}

extern "C" void kernel_launch(void* const* d_in, const int* in_sizes, int n_in,
                              void* d_out, int out_size, void* d_ws, size_t ws_size,
                              hipStream_t stream) {
  (void)n_in; (void)out_size; (void)ws_size;
  const float* x   = (const float*)d_in[0];
  const float* att = (const float*)d_in[1];
  const float* W[9]; const float* B[9];
  for (int i=0;i<9;i++){ W[i]=(const float*)d_in[3+2*i]; B[i]=(const float*)d_in[4+2*i]; }
  const float* fcW  = (const float*)d_in[21];
  const float* fcB  = (const float*)d_in[22];
  const float* bn_g = (const float*)d_in[23];
  const float* bn_b = (const float*)d_in[24];
  const float* bn_rm= (const float*)d_in[25];
  const float* bn_rv= (const float*)d_in[26];
  float* out = (float*)d_out;

  const int G = in_sizes[1] / 17;
  const int G2 = (G+1)&~1;

  // ws layout
  char* ws = (char*)d_ws;
  f16*   wt   = (f16*)(ws);                       // 430080 B
  f16*   fcWh = (f16*)(ws + 430080);              // 786432 B -> ends 1216512
  float* bnsc = (float*)(ws + 1216512);           // 6144 B
  float* bnsh = (float*)(ws + 1222656);           // 6144 B
  float* bcat = (float*)(ws + 1228800);           // 5376 B -> ends 1234176
  f16*   Ath  = (f16*)(ws + 1234176);             // 6144 B -> ends 1240320
  float* attp = (float*)(ws + 1240320);           // G2*24*4 B
  size_t poolOff = (1240320 + (size_t)G2*96 + 255) & ~(size_t)255;
  f16* pooled = (f16*)(ws + poolOff);             // G*1536*2 B

  prep_kernel<<<2048, 256, 0, stream>>>(
      W[0],W[1],W[2],W[3],W[4],W[5],W[6],W[7],W[8],
      B[0],B[1],B[2],B[3],B[4],B[5],B[6],B[7],B[8],
      fcW, bn_g, bn_b, bn_rm, bn_rv, att,
      wt, Ath, fcWh, bnsc, bnsh, bcat, attp, G);

  const int gb = (G + 1) / 2;
  gcn_kernel<<<gb, 256, 0, stream>>>(
      x, wt, Ath, attp, bcat, pooled, G);

  head_kernel<<<(G + 15)/16, 256, 0, stream>>>(
      pooled, fcWh, fcB, bnsc, bnsh, out, G);
}